// Round 2
// baseline (1351.057 us; speedup 1.0000x reference)
//
#include <hip/hip_runtime.h>
#include <hip/hip_bf16.h>

#define N_ENT  100000
#define N_REL2 1000
#define H      256
#define E_EDGES 320000
#define REL_ROWS_PAD 1024   // 1000 rel rows padded to 64-row multiple
#define DEG_BINS 64

typedef unsigned short u16;
typedef short bf16x8 __attribute__((ext_vector_type(8)));
typedef float floatx4 __attribute__((ext_vector_type(4)));

__device__ __forceinline__ u16 f2bf(float f) {
    unsigned x = __float_as_uint(f);
    unsigned r = (x + 0x7fffu + ((x >> 16) & 1u)) >> 16;  // RNE
    return (u16)r;
}

__device__ __forceinline__ ushort4 pack4(float4 v, float s) {
    return make_ushort4(f2bf(v.x * s), f2bf(v.y * s), f2bf(v.z * s), f2bf(v.w * s));
}

__device__ __forceinline__ float fast_tanh(float x) {
    float e = __expf(2.0f * x);
    return 1.0f - 2.0f * __builtin_amdgcn_rcpf(e + 1.0f);
}

__device__ __forceinline__ void async16(u16* lds, const u16* g) {
    __builtin_amdgcn_global_load_lds(
        (const __attribute__((address_space(1))) void*)g,
        (__attribute__((address_space(3))) void*)lds, 16, 0, 0);
}

// ---------------- CSR build ----------------

__global__ void hist_kernel(const int* __restrict__ dst, int* __restrict__ counts) {
    int i = blockIdx.x * blockDim.x + threadIdx.x;
    if (i < E_EDGES) atomicAdd(&counts[dst[i]], 1);
}

__global__ void scan1_kernel(const int* __restrict__ counts, int* __restrict__ offsets,
                             int* __restrict__ bsum) {
    __shared__ int buf[1024];
    int t = threadIdx.x, i = blockIdx.x * 1024 + t;
    int v = (i < N_ENT) ? counts[i] : 0;
    int acc = v;
    buf[t] = acc;
    __syncthreads();
    for (int off = 1; off < 1024; off <<= 1) {
        int u = (t >= off) ? buf[t - off] : 0;
        __syncthreads();
        acc += u;
        buf[t] = acc;
        __syncthreads();
    }
    if (i < N_ENT) offsets[i] = acc - v;  // exclusive within block
    if (t == 1023) bsum[blockIdx.x] = acc;
}

__global__ void scan2_kernel(int* __restrict__ bsum, int* __restrict__ offsets) {
    __shared__ int s[128];
    int t = threadIdx.x;
    s[t] = (t < 98) ? bsum[t] : 0;
    __syncthreads();
    if (t == 0) {
        int run = 0;
        for (int b = 0; b < 98; ++b) { int x = s[b]; s[b] = run; run += x; }
        offsets[N_ENT] = run;
    }
    __syncthreads();
    if (t < 98) bsum[t] = s[t];
}

__global__ void scan3_kernel(int* __restrict__ offsets, const int* __restrict__ bsum) {
    int i = blockIdx.x * 1024 + threadIdx.x;
    if (i < N_ENT && blockIdx.x > 0) offsets[i] += bsum[blockIdx.x];
}

// ---------------- destination degree sort (counting sort, 64 bins) ----------------
// scatter waves process dsts in degree order so the 4 waves of a block have
// (near-)equal trip counts -> uniform block retirement -> high achieved occupancy.

__global__ void deghist_kernel(const int* __restrict__ counts, int* __restrict__ dbin) {
    int i = blockIdx.x * blockDim.x + threadIdx.x;
    if (i < N_ENT) {
        int b = counts[i]; if (b > DEG_BINS - 1) b = DEG_BINS - 1;
        atomicAdd(&dbin[b], 1);
    }
}

__global__ void degscan_kernel(const int* __restrict__ dbin, int* __restrict__ doff) {
    if (threadIdx.x == 0) {
        int run = 0;
        for (int b = 0; b < DEG_BINS; ++b) { doff[b] = run; run += dbin[b]; }
    }
}

__global__ void degplace_kernel(const int* __restrict__ counts, int* __restrict__ doff,
                                int* __restrict__ dorder) {
    int i = blockIdx.x * blockDim.x + threadIdx.x;
    if (i < N_ENT) {
        int b = counts[i]; if (b > DEG_BINS - 1) b = DEG_BINS - 1;
        int pos = atomicAdd(&doff[b], 1);
        dorder[pos] = i;
    }
}

// place: resolve the whole per-edge metadata chain HERE (edge-parallel, coalesced
// reads) so scatter's per-edge chain is ONE 8B load: meta[pos] = {node_id[src], rel_id}
__global__ void place_kernel(const int* __restrict__ dst, const int* __restrict__ src,
                             const int* __restrict__ rel_id, const int* __restrict__ node_id,
                             const int* __restrict__ offsets,
                             int* __restrict__ counts, int2* __restrict__ meta) {
    int i = blockIdx.x * blockDim.x + threadIdx.x;
    if (i < E_EDGES) {
        int d = dst[i];
        int old = atomicSub(&counts[d], 1);
        meta[offsets[d] + old - 1] = make_int2(node_id[src[i]], rel_id[i]);
    }
}

// ---------------- weight prep ----------------
// B-fragment order for mfma_f32_16x16x32_bf16 (verified R1 of prior session):
// dst[((ntile*8+kstep)*64+lane)*8+j] = bf16(W[kstep*32+(lane>>4)*8+j][ntile*16+(lane&15)])
__global__ void swz_kernel(const float* __restrict__ w0, const float* __restrict__ w1,
                           const float* __restrict__ w2, const float* __restrict__ w3,
                           u16* __restrict__ dstp) {
    int t = blockIdx.x * blockDim.x + threadIdx.x;
    if (t >= 4 * H * H) return;
    int mat = t >> 16;
    int r = t & 65535;
    int j = r & 7, lane = (r >> 3) & 63, kstep = (r >> 9) & 7, ntile = r >> 12;
    int k = kstep * 32 + (lane >> 4) * 8 + j;
    int n = ntile * 16 + (lane & 15);
    const float* W = (mat == 0) ? w0 : (mat == 1) ? w1 : (mat == 2) ? w2 : w3;
    dstp[t] = f2bf(W[k * H + n]);
}

// rel_emb -> bf16, row-major with intra-row XOR chunk swizzle (same layout as agg):
// u16 index row*256 + kk holds rel[row][kk ^ ((row&7)<<3)]
__global__ void relbf_kernel(const float* __restrict__ rel, u16* __restrict__ out) {
    int t = blockIdx.x * blockDim.x + threadIdx.x;
    if (t >= REL_ROWS_PAD * H) return;
    int row = t >> 8, kk = t & 255;
    int k = kk ^ ((row & 7) << 3);
    float v = (row < N_REL2) ? rel[row * H + k] : 0.f;
    out[t] = f2bf(v);
}

// ---------------- fused per-dst scores + softmax + segment-sum ----------------
// one wave per destination (taken from the degree-sorted order); 4 waves/block.
__global__ __launch_bounds__(256) void scatter_kernel(
    const float* __restrict__ ent, const float* __restrict__ rel,
    const int2* __restrict__ meta, const int* __restrict__ node_id,
    const int* __restrict__ offsets, const int* __restrict__ dorder,
    u16* __restrict__ agg_e, u16* __restrict__ agg_n, u16* __restrict__ agg_c) {
    int lane = threadIdx.x & 63;
    int wv = __builtin_amdgcn_readfirstlane(threadIdx.x >> 6);
    int w = blockIdx.x * 4 + wv;
    if (w >= N_ENT) return;
    int d = dorder[w];
    int nid = node_id[d];
    int p0 = offsets[d], p1 = offsets[d + 1];
    float4 hd = ((const float4*)(ent + (size_t)nid * H))[lane];
    float me = -INFINITY, mn = -INFINITY, mc = -INFINITY;
    float le = 0.f, ln = 0.f, lc = 0.f;
    float4 ae = make_float4(0, 0, 0, 0), an = make_float4(0, 0, 0, 0), ac = make_float4(0, 0, 0, 0);

    for (int pc = p0; pc < p1; pc += 4) {
        int cnt = p1 - pc; if (cnt > 4) cnt = 4;
        int2 md[4];
#pragma unroll
        for (int j = 0; j < 4; ++j) if (j < cnt) md[j] = meta[pc + j];
        float4 ev[4], sv[4];
#pragma unroll
        for (int j = 0; j < 4; ++j) if (j < cnt) {
            ev[j] = ((const float4*)(rel + (size_t)md[j].y * H))[lane];
            sv[j] = ((const float4*)(ent + (size_t)md[j].x * H))[lane];
        }
#pragma unroll
        for (int j = 0; j < 4; ++j) if (j < cnt) {
            float4 e4 = ev[j], s4 = sv[j];
            float4 c4 = make_float4(e4.x * s4.x, e4.y * s4.y, e4.z * s4.z, e4.w * s4.w);
            float de = e4.x * hd.x + e4.y * hd.y + e4.z * hd.z + e4.w * hd.w;
            float dn = s4.x * hd.x + s4.y * hd.y + s4.z * hd.z + s4.w * hd.w;
            float dc = c4.x * hd.x + c4.y * hd.y + c4.z * hd.z + c4.w * hd.w;
#pragma unroll
            for (int o = 32; o > 0; o >>= 1) {
                de += __shfl_xor(de, o);
                dn += __shfl_xor(dn, o);
                dc += __shfl_xor(dc, o);
            }
            { float nm = fmaxf(me, de); float s = __expf(me - nm); float pr = __expf(de - nm);
              le = le * s + pr;
              ae.x = ae.x * s + pr * e4.x; ae.y = ae.y * s + pr * e4.y;
              ae.z = ae.z * s + pr * e4.z; ae.w = ae.w * s + pr * e4.w; me = nm; }
            { float nm = fmaxf(mn, dn); float s = __expf(mn - nm); float pr = __expf(dn - nm);
              ln = ln * s + pr;
              an.x = an.x * s + pr * s4.x; an.y = an.y * s + pr * s4.y;
              an.z = an.z * s + pr * s4.z; an.w = an.w * s + pr * s4.w; mn = nm; }
            { float nm = fmaxf(mc, dc); float s = __expf(mc - nm); float pr = __expf(dc - nm);
              lc = lc * s + pr;
              ac.x = ac.x * s + pr * c4.x; ac.y = ac.y * s + pr * c4.y;
              ac.z = ac.z * s + pr * c4.z; ac.w = ac.w * s + pr * c4.w; mc = nm; }
        }
    }
    float ie = (le > 0.f) ? 1.0f / le : 0.f;
    float in_ = (ln > 0.f) ? 1.0f / ln : 0.f;
    float ic = (lc > 0.f) ? 1.0f / lc : 0.f;
    // row-major store, one contiguous 512B line-aligned write per wave per array.
    // intra-row XOR chunk swizzle (bits 4-6) so the GEMM's ds_read_b128 A-fragment
    // reads are bank-conflict-light; store coalescing unaffected (same 512B region).
    size_t rowb = (size_t)d * (H * 2);
    int boff = (lane * 8) ^ ((d & 7) << 4);
    *(ushort4*)((char*)agg_e + rowb + boff) = pack4(ae, ie);
    *(ushort4*)((char*)agg_n + rowb + boff) = pack4(an, in_);
    *(ushort4*)((char*)agg_c + rowb + boff) = pack4(ac, ic);
}

// ---------------- fused multi-layer GEMM epilogue ----------------
// out[r,:] = base[r,:] + sum_l tanh(A_l[r,:] @ W_l)   (raw if !do_tanh)
// 64 rows x 256 cols per block, 4 waves; A rows staged linearly to LDS (rows are
// pre-swizzled in global, rule #21), fragments read with the inverse XOR.
__global__ __launch_bounds__(256, 2) void gemm_kernel(
    const u16* __restrict__ A0, const u16* __restrict__ A1, const u16* __restrict__ A2,
    const u16* __restrict__ W0, const u16* __restrict__ W1, const u16* __restrict__ W2,
    const float* __restrict__ base, float* __restrict__ out,
    int n_real, int n_layers, int do_tanh) {
    __shared__ u16 lA[2][16384];  // 2 x 32KB: 64 rows x 512B row-major (swizzled)
    int tid = threadIdx.x;
    int lane = tid & 63;
    int wv = tid >> 6;
    int m = lane & 15;
    int quad = lane >> 4;
    int r0 = blockIdx.x * 64;
    const u16* As[3] = { A0, A1, A2 };
    const u16* Ws[3] = { W0, W1, W2 };

    float outacc[4][4][4];
#pragma unroll
    for (int rt = 0; rt < 4; ++rt)
#pragma unroll
        for (int ct = 0; ct < 4; ++ct) {
            int grow = r0 + rt * 16 + quad * 4;
            int gcol = wv * 64 + ct * 16 + m;
#pragma unroll
            for (int r = 0; r < 4; ++r) {
                float v = 0.f;
                if (base != nullptr && (grow + r) < n_real) v = base[(size_t)(grow + r) * H + gcol];
                outacc[rt][ct][r] = v;
            }
        }

    // stage layer 0 into buf 0 (linear 32KB copy, async to LDS)
    {
        const u16* gsrc = As[0] + (size_t)blockIdx.x * 64 * H;
#pragma unroll
        for (int rnd = 0; rnd < 8; ++rnd) {
            int off8 = (rnd * 256 + tid) * 8;
            async16(&lA[0][off8], gsrc + off8);
        }
    }

    int mrow = m * 512;          // row byte base within a 16-row fragment
    int swz = (m & 7) << 4;      // inverse of the store-side XOR

    for (int l = 0; l < n_layers; ++l) {
        __syncthreads();  // buf[l&1] staged; prev layer's ds_reads complete
        if (l + 1 < n_layers) {
            const u16* gsrc = As[l + 1] + (size_t)blockIdx.x * 64 * H;
            u16* dstb = lA[(l + 1) & 1];
#pragma unroll
            for (int rnd = 0; rnd < 8; ++rnd) {
                int off8 = (rnd * 256 + tid) * 8;
                async16(&dstb[off8], gsrc + off8);
            }
        }
        const char* lbc = (const char*)lA[l & 1];
        const u16* Wl = Ws[l];

        floatx4 lacc[4][4];
#pragma unroll
        for (int rt = 0; rt < 4; ++rt)
#pragma unroll
            for (int ct = 0; ct < 4; ++ct)
#pragma unroll
                for (int r = 0; r < 4; ++r) lacc[rt][ct][r] = 0.f;

#pragma unroll
        for (int ks = 0; ks < 8; ++ks) {
            bf16x8 af[4], bfr[4];
#pragma unroll
            for (int rt = 0; rt < 4; ++rt)
                af[rt] = *(const bf16x8*)(lbc + rt * 8192 + mrow + ((ks * 64 + quad * 16) ^ swz));
#pragma unroll
            for (int ct = 0; ct < 4; ++ct)
                bfr[ct] = *(const bf16x8*)(Wl + (((size_t)(wv * 4 + ct) * 8 + ks) * 64 + lane) * 8);
#pragma unroll
            for (int rt = 0; rt < 4; ++rt)
#pragma unroll
                for (int ct = 0; ct < 4; ++ct)
                    lacc[rt][ct] = __builtin_amdgcn_mfma_f32_16x16x32_bf16(
                        af[rt], bfr[ct], lacc[rt][ct], 0, 0, 0);
        }

#pragma unroll
        for (int rt = 0; rt < 4; ++rt)
#pragma unroll
            for (int ct = 0; ct < 4; ++ct)
#pragma unroll
                for (int r = 0; r < 4; ++r) {
                    float v = lacc[rt][ct][r];
                    outacc[rt][ct][r] += do_tanh ? fast_tanh(v) : v;
                }
    }

#pragma unroll
    for (int rt = 0; rt < 4; ++rt)
#pragma unroll
        for (int ct = 0; ct < 4; ++ct) {
            int grow = r0 + rt * 16 + quad * 4;
            int gcol = wv * 64 + ct * 16 + m;
#pragma unroll
            for (int r = 0; r < 4; ++r)
                if ((grow + r) < n_real) out[(size_t)(grow + r) * H + gcol] = outacc[rt][ct][r];
        }
}

// ---------------- launch ----------------

extern "C" void kernel_launch(void* const* d_in, const int* in_sizes, int n_in,
                              void* d_out, int out_size, void* d_ws, size_t ws_size,
                              hipStream_t stream) {
    (void)in_sizes; (void)n_in; (void)out_size; (void)ws_size;
    const float* ent    = (const float*)d_in[0];
    const float* rel    = (const float*)d_in[1];
    const float* w_edge = (const float*)d_in[2];
    const float* w_node = (const float*)d_in[3];
    const float* w_comp = (const float*)d_in[4];
    const float* rel_w  = (const float*)d_in[5];
    const int* src      = (const int*)d_in[6];
    const int* dst      = (const int*)d_in[7];
    const int* rel_id   = (const int*)d_in[8];
    const int* node_id  = (const int*)d_in[9];

    char* wsb = (char*)d_ws;
    size_t o = 0;
    auto alloc = [&](size_t bytes) -> char* {
        char* p = wsb + o;
        o = (o + bytes + 255) & ~(size_t)255;
        return p;
    };
    int* counts  = (int*)alloc((size_t)N_ENT * 4);
    int* offsets = (int*)alloc((size_t)(N_ENT + 1) * 4);
    int* bsum    = (int*)alloc(128 * 4);
    int2* meta   = (int2*)alloc((size_t)E_EDGES * 8);
    int* dbin    = (int*)alloc(DEG_BINS * 4);
    int* doff    = (int*)alloc(DEG_BINS * 4);
    int* dorder  = (int*)alloc((size_t)N_ENT * 4);
    u16* agg_e   = (u16*)alloc((size_t)N_ENT * H * 2);
    u16* agg_n   = (u16*)alloc((size_t)N_ENT * H * 2);
    u16* agg_c   = (u16*)alloc((size_t)N_ENT * H * 2);
    u16* wswz    = (u16*)alloc((size_t)4 * H * H * 2);
    u16* relbf   = (u16*)alloc((size_t)REL_ROWS_PAD * H * 2);
    (void)alloc(65536);  // overrun pad for tail-block A staging reads

    float* out_ent = (float*)d_out;
    float* out_rel = out_ent + (size_t)N_ENT * H;

    hipMemsetAsync(counts, 0, (size_t)N_ENT * 4, stream);
    hipMemsetAsync(dbin, 0, DEG_BINS * 4, stream);
    hist_kernel<<<(E_EDGES + 255) / 256, 256, 0, stream>>>(dst, counts);
    scan1_kernel<<<98, 1024, 0, stream>>>(counts, offsets, bsum);
    scan2_kernel<<<1, 128, 0, stream>>>(bsum, offsets);
    scan3_kernel<<<98, 1024, 0, stream>>>(offsets, bsum);
    deghist_kernel<<<(N_ENT + 255) / 256, 256, 0, stream>>>(counts, dbin);
    degscan_kernel<<<1, 64, 0, stream>>>(dbin, doff);
    degplace_kernel<<<(N_ENT + 255) / 256, 256, 0, stream>>>(counts, doff, dorder);
    place_kernel<<<(E_EDGES + 255) / 256, 256, 0, stream>>>(dst, src, rel_id, node_id,
                                                            offsets, counts, meta);
    swz_kernel<<<(4 * H * H + 255) / 256, 256, 0, stream>>>(w_edge, w_node, w_comp, rel_w, wswz);
    relbf_kernel<<<(REL_ROWS_PAD * H + 255) / 256, 256, 0, stream>>>(rel, relbf);
    scatter_kernel<<<N_ENT / 4, 256, 0, stream>>>(ent, rel, meta, node_id, offsets, dorder,
                                                  agg_e, agg_n, agg_c);
    gemm_kernel<<<(N_ENT + 63) / 64, 256, 0, stream>>>(agg_e, agg_n, agg_c,
                                                       wswz, wswz + H * H, wswz + 2 * H * H,
                                                       ent, out_ent, N_ENT, 3, 1);
    gemm_kernel<<<(N_REL2 + 63) / 64, 256, 0, stream>>>(relbf, relbf, relbf,
                                                        wswz + 3 * H * H, wswz + 3 * H * H, wswz + 3 * H * H,
                                                        nullptr, out_rel, N_REL2, 1, 0);
}

// Round 3
// 501.711 us; speedup vs baseline: 2.6929x; 2.6929x over previous
//
#include <hip/hip_runtime.h>
#include <hip/hip_bf16.h>

#define N_ENT  100000
#define N_REL2 1000
#define H      256
#define E_EDGES 320000
#define REL_ROWS_PAD 1024   // 1000 rel rows padded to 64-row multiple
#define DEG_BINS 64

typedef unsigned short u16;
typedef short bf16x8 __attribute__((ext_vector_type(8)));
typedef float floatx4 __attribute__((ext_vector_type(4)));

__device__ __forceinline__ u16 f2bf(float f) {
    unsigned x = __float_as_uint(f);
    unsigned r = (x + 0x7fffu + ((x >> 16) & 1u)) >> 16;  // RNE
    return (u16)r;
}

__device__ __forceinline__ ushort4 pack4(float4 v, float s) {
    return make_ushort4(f2bf(v.x * s), f2bf(v.y * s), f2bf(v.z * s), f2bf(v.w * s));
}

__device__ __forceinline__ float fast_tanh(float x) {
    float e = __expf(2.0f * x);
    return 1.0f - 2.0f * __builtin_amdgcn_rcpf(e + 1.0f);
}

__device__ __forceinline__ void async16(u16* lds, const u16* g) {
    __builtin_amdgcn_global_load_lds(
        (const __attribute__((address_space(1))) void*)g,
        (__attribute__((address_space(3))) void*)lds, 16, 0, 0);
}

// ---------------- CSR build ----------------

__global__ void hist_kernel(const int* __restrict__ dst, int* __restrict__ counts) {
    int i = blockIdx.x * blockDim.x + threadIdx.x;
    if (i < E_EDGES) atomicAdd(&counts[dst[i]], 1);
}

__global__ void scan1_kernel(const int* __restrict__ counts, int* __restrict__ offsets,
                             int* __restrict__ bsum) {
    __shared__ int buf[1024];
    int t = threadIdx.x, i = blockIdx.x * 1024 + t;
    int v = (i < N_ENT) ? counts[i] : 0;
    int acc = v;
    buf[t] = acc;
    __syncthreads();
    for (int off = 1; off < 1024; off <<= 1) {
        int u = (t >= off) ? buf[t - off] : 0;
        __syncthreads();
        acc += u;
        buf[t] = acc;
        __syncthreads();
    }
    if (i < N_ENT) offsets[i] = acc - v;  // exclusive within block
    if (t == 1023) bsum[blockIdx.x] = acc;
}

__global__ void scan2_kernel(int* __restrict__ bsum, int* __restrict__ offsets) {
    __shared__ int s[128];
    int t = threadIdx.x;
    s[t] = (t < 98) ? bsum[t] : 0;
    __syncthreads();
    if (t == 0) {
        int run = 0;
        for (int b = 0; b < 98; ++b) { int x = s[b]; s[b] = run; run += x; }
        offsets[N_ENT] = run;
    }
    __syncthreads();
    if (t < 98) bsum[t] = s[t];
}

__global__ void scan3_kernel(int* __restrict__ offsets, const int* __restrict__ bsum) {
    int i = blockIdx.x * 1024 + threadIdx.x;
    if (i < N_ENT && blockIdx.x > 0) offsets[i] += bsum[blockIdx.x];
}

// ---------------- destination degree sort (counting sort, 64 bins) ----------------
// Two-level aggregation (Guideline 12): LDS histogram per block, ONE global atomic
// per (block, bin). R2's flat version (100k device atomics on 64 addresses) cost
// 2x429 us of pure cross-XCD RMW serialization.

__global__ void deghist_kernel(const int* __restrict__ counts, int* __restrict__ dbin) {
    __shared__ int lh[DEG_BINS];
    int t = threadIdx.x;
    if (t < DEG_BINS) lh[t] = 0;
    __syncthreads();
    int i = blockIdx.x * blockDim.x + t;
    if (i < N_ENT) {
        int b = counts[i]; if (b > DEG_BINS - 1) b = DEG_BINS - 1;
        atomicAdd(&lh[b], 1);          // LDS atomic
    }
    __syncthreads();
    if (t < DEG_BINS && lh[t]) atomicAdd(&dbin[t], lh[t]);  // 64 global atomics/block
}

__global__ void degscan_kernel(const int* __restrict__ dbin, int* __restrict__ doff) {
    if (threadIdx.x == 0) {
        int run = 0;
        for (int b = 0; b < DEG_BINS; ++b) { doff[b] = run; run += dbin[b]; }
    }
}

__global__ void degplace_kernel(const int* __restrict__ counts, int* __restrict__ doff,
                                int* __restrict__ dorder) {
    __shared__ int lh[DEG_BINS];
    __shared__ int lbase[DEG_BINS];
    int t = threadIdx.x;
    if (t < DEG_BINS) lh[t] = 0;
    __syncthreads();
    int i = blockIdx.x * blockDim.x + t;
    int b = 0, myidx = 0;
    if (i < N_ENT) {
        b = counts[i]; if (b > DEG_BINS - 1) b = DEG_BINS - 1;
        myidx = atomicAdd(&lh[b], 1);  // LDS atomic: intra-block rank
    }
    __syncthreads();
    if (t < DEG_BINS) lbase[t] = lh[t] ? atomicAdd(&doff[t], lh[t]) : 0;  // range reserve
    __syncthreads();
    if (i < N_ENT) dorder[lbase[b] + myidx] = i;
}

// place: resolve the whole per-edge metadata chain HERE (edge-parallel, coalesced
// reads) so scatter's per-edge chain is ONE 8B load: meta[pos] = {node_id[src], rel_id}
__global__ void place_kernel(const int* __restrict__ dst, const int* __restrict__ src,
                             const int* __restrict__ rel_id, const int* __restrict__ node_id,
                             const int* __restrict__ offsets,
                             int* __restrict__ counts, int2* __restrict__ meta) {
    int i = blockIdx.x * blockDim.x + threadIdx.x;
    if (i < E_EDGES) {
        int d = dst[i];
        int old = atomicSub(&counts[d], 1);
        meta[offsets[d] + old - 1] = make_int2(node_id[src[i]], rel_id[i]);
    }
}

// ---------------- weight prep ----------------
// B-fragment order for mfma_f32_16x16x32_bf16 (verified R1 of prior session):
// dst[((ntile*8+kstep)*64+lane)*8+j] = bf16(W[kstep*32+(lane>>4)*8+j][ntile*16+(lane&15)])
__global__ void swz_kernel(const float* __restrict__ w0, const float* __restrict__ w1,
                           const float* __restrict__ w2, const float* __restrict__ w3,
                           u16* __restrict__ dstp) {
    int t = blockIdx.x * blockDim.x + threadIdx.x;
    if (t >= 4 * H * H) return;
    int mat = t >> 16;
    int r = t & 65535;
    int j = r & 7, lane = (r >> 3) & 63, kstep = (r >> 9) & 7, ntile = r >> 12;
    int k = kstep * 32 + (lane >> 4) * 8 + j;
    int n = ntile * 16 + (lane & 15);
    const float* W = (mat == 0) ? w0 : (mat == 1) ? w1 : (mat == 2) ? w2 : w3;
    dstp[t] = f2bf(W[k * H + n]);
}

// rel_emb -> bf16, row-major with intra-row XOR chunk swizzle (same layout as agg):
// u16 index row*256 + kk holds rel[row][kk ^ ((row&7)<<3)]
__global__ void relbf_kernel(const float* __restrict__ rel, u16* __restrict__ out) {
    int t = blockIdx.x * blockDim.x + threadIdx.x;
    if (t >= REL_ROWS_PAD * H) return;
    int row = t >> 8, kk = t & 255;
    int k = kk ^ ((row & 7) << 3);
    float v = (row < N_REL2) ? rel[row * H + k] : 0.f;
    out[t] = f2bf(v);
}

// ---------------- fused per-dst scores + softmax + segment-sum ----------------
// one wave per destination (taken from the degree-sorted order); 4 waves/block.
__global__ __launch_bounds__(256) void scatter_kernel(
    const float* __restrict__ ent, const float* __restrict__ rel,
    const int2* __restrict__ meta, const int* __restrict__ node_id,
    const int* __restrict__ offsets, const int* __restrict__ dorder,
    u16* __restrict__ agg_e, u16* __restrict__ agg_n, u16* __restrict__ agg_c) {
    int lane = threadIdx.x & 63;
    int wv = __builtin_amdgcn_readfirstlane(threadIdx.x >> 6);
    int w = blockIdx.x * 4 + wv;
    if (w >= N_ENT) return;
    int d = dorder[w];
    int nid = node_id[d];
    int p0 = offsets[d], p1 = offsets[d + 1];
    float4 hd = ((const float4*)(ent + (size_t)nid * H))[lane];
    float me = -INFINITY, mn = -INFINITY, mc = -INFINITY;
    float le = 0.f, ln = 0.f, lc = 0.f;
    float4 ae = make_float4(0, 0, 0, 0), an = make_float4(0, 0, 0, 0), ac = make_float4(0, 0, 0, 0);

    for (int pc = p0; pc < p1; pc += 4) {
        int cnt = p1 - pc; if (cnt > 4) cnt = 4;
        int2 md[4];
#pragma unroll
        for (int j = 0; j < 4; ++j) if (j < cnt) md[j] = meta[pc + j];
        float4 ev[4], sv[4];
#pragma unroll
        for (int j = 0; j < 4; ++j) if (j < cnt) {
            ev[j] = ((const float4*)(rel + (size_t)md[j].y * H))[lane];
            sv[j] = ((const float4*)(ent + (size_t)md[j].x * H))[lane];
        }
#pragma unroll
        for (int j = 0; j < 4; ++j) if (j < cnt) {
            float4 e4 = ev[j], s4 = sv[j];
            float4 c4 = make_float4(e4.x * s4.x, e4.y * s4.y, e4.z * s4.z, e4.w * s4.w);
            float de = e4.x * hd.x + e4.y * hd.y + e4.z * hd.z + e4.w * hd.w;
            float dn = s4.x * hd.x + s4.y * hd.y + s4.z * hd.z + s4.w * hd.w;
            float dc = c4.x * hd.x + c4.y * hd.y + c4.z * hd.z + c4.w * hd.w;
#pragma unroll
            for (int o = 32; o > 0; o >>= 1) {
                de += __shfl_xor(de, o);
                dn += __shfl_xor(dn, o);
                dc += __shfl_xor(dc, o);
            }
            { float nm = fmaxf(me, de); float s = __expf(me - nm); float pr = __expf(de - nm);
              le = le * s + pr;
              ae.x = ae.x * s + pr * e4.x; ae.y = ae.y * s + pr * e4.y;
              ae.z = ae.z * s + pr * e4.z; ae.w = ae.w * s + pr * e4.w; me = nm; }
            { float nm = fmaxf(mn, dn); float s = __expf(mn - nm); float pr = __expf(dn - nm);
              ln = ln * s + pr;
              an.x = an.x * s + pr * s4.x; an.y = an.y * s + pr * s4.y;
              an.z = an.z * s + pr * s4.z; an.w = an.w * s + pr * s4.w; mn = nm; }
            { float nm = fmaxf(mc, dc); float s = __expf(mc - nm); float pr = __expf(dc - nm);
              lc = lc * s + pr;
              ac.x = ac.x * s + pr * c4.x; ac.y = ac.y * s + pr * c4.y;
              ac.z = ac.z * s + pr * c4.z; ac.w = ac.w * s + pr * c4.w; mc = nm; }
        }
    }
    float ie = (le > 0.f) ? 1.0f / le : 0.f;
    float in_ = (ln > 0.f) ? 1.0f / ln : 0.f;
    float ic = (lc > 0.f) ? 1.0f / lc : 0.f;
    // row-major store, one contiguous 512B line-aligned write per wave per array.
    // intra-row XOR chunk swizzle (bits 4-6) so the GEMM's ds_read_b128 A-fragment
    // reads are bank-conflict-light; store coalescing unaffected (same 512B region).
    size_t rowb = (size_t)d * (H * 2);
    int boff = (lane * 8) ^ ((d & 7) << 4);
    *(ushort4*)((char*)agg_e + rowb + boff) = pack4(ae, ie);
    *(ushort4*)((char*)agg_n + rowb + boff) = pack4(an, in_);
    *(ushort4*)((char*)agg_c + rowb + boff) = pack4(ac, ic);
}

// ---------------- fused multi-layer GEMM epilogue ----------------
// out[r,:] = base[r,:] + sum_l tanh(A_l[r,:] @ W_l)   (raw if !do_tanh)
// 64 rows x 256 cols per block, 4 waves; A rows staged linearly to LDS (rows are
// pre-swizzled in global, rule #21), fragments read with the inverse XOR.
__global__ __launch_bounds__(256, 2) void gemm_kernel(
    const u16* __restrict__ A0, const u16* __restrict__ A1, const u16* __restrict__ A2,
    const u16* __restrict__ W0, const u16* __restrict__ W1, const u16* __restrict__ W2,
    const float* __restrict__ base, float* __restrict__ out,
    int n_real, int n_layers, int do_tanh) {
    __shared__ u16 lA[2][16384];  // 2 x 32KB: 64 rows x 512B row-major (swizzled)
    int tid = threadIdx.x;
    int lane = tid & 63;
    int wv = tid >> 6;
    int m = lane & 15;
    int quad = lane >> 4;
    int r0 = blockIdx.x * 64;
    const u16* As[3] = { A0, A1, A2 };
    const u16* Ws[3] = { W0, W1, W2 };

    float outacc[4][4][4];
#pragma unroll
    for (int rt = 0; rt < 4; ++rt)
#pragma unroll
        for (int ct = 0; ct < 4; ++ct) {
            int grow = r0 + rt * 16 + quad * 4;
            int gcol = wv * 64 + ct * 16 + m;
#pragma unroll
            for (int r = 0; r < 4; ++r) {
                float v = 0.f;
                if (base != nullptr && (grow + r) < n_real) v = base[(size_t)(grow + r) * H + gcol];
                outacc[rt][ct][r] = v;
            }
        }

    // stage layer 0 into buf 0 (linear 32KB copy, async to LDS)
    {
        const u16* gsrc = As[0] + (size_t)blockIdx.x * 64 * H;
#pragma unroll
        for (int rnd = 0; rnd < 8; ++rnd) {
            int off8 = (rnd * 256 + tid) * 8;
            async16(&lA[0][off8], gsrc + off8);
        }
    }

    int mrow = m * 512;          // row byte base within a 16-row fragment
    int swz = (m & 7) << 4;      // inverse of the store-side XOR

    for (int l = 0; l < n_layers; ++l) {
        __syncthreads();  // buf[l&1] staged; prev layer's ds_reads complete
        if (l + 1 < n_layers) {
            const u16* gsrc = As[l + 1] + (size_t)blockIdx.x * 64 * H;
            u16* dstb = lA[(l + 1) & 1];
#pragma unroll
            for (int rnd = 0; rnd < 8; ++rnd) {
                int off8 = (rnd * 256 + tid) * 8;
                async16(&dstb[off8], gsrc + off8);
            }
        }
        const char* lbc = (const char*)lA[l & 1];
        const u16* Wl = Ws[l];

        floatx4 lacc[4][4];
#pragma unroll
        for (int rt = 0; rt < 4; ++rt)
#pragma unroll
            for (int ct = 0; ct < 4; ++ct)
#pragma unroll
                for (int r = 0; r < 4; ++r) lacc[rt][ct][r] = 0.f;

#pragma unroll
        for (int ks = 0; ks < 8; ++ks) {
            bf16x8 af[4], bfr[4];
#pragma unroll
            for (int rt = 0; rt < 4; ++rt)
                af[rt] = *(const bf16x8*)(lbc + rt * 8192 + mrow + ((ks * 64 + quad * 16) ^ swz));
#pragma unroll
            for (int ct = 0; ct < 4; ++ct)
                bfr[ct] = *(const bf16x8*)(Wl + (((size_t)(wv * 4 + ct) * 8 + ks) * 64 + lane) * 8);
#pragma unroll
            for (int rt = 0; rt < 4; ++rt)
#pragma unroll
                for (int ct = 0; ct < 4; ++ct)
                    lacc[rt][ct] = __builtin_amdgcn_mfma_f32_16x16x32_bf16(
                        af[rt], bfr[ct], lacc[rt][ct], 0, 0, 0);
        }

#pragma unroll
        for (int rt = 0; rt < 4; ++rt)
#pragma unroll
            for (int ct = 0; ct < 4; ++ct)
#pragma unroll
                for (int r = 0; r < 4; ++r) {
                    float v = lacc[rt][ct][r];
                    outacc[rt][ct][r] += do_tanh ? fast_tanh(v) : v;
                }
    }

#pragma unroll
    for (int rt = 0; rt < 4; ++rt)
#pragma unroll
        for (int ct = 0; ct < 4; ++ct) {
            int grow = r0 + rt * 16 + quad * 4;
            int gcol = wv * 64 + ct * 16 + m;
#pragma unroll
            for (int r = 0; r < 4; ++r)
                if ((grow + r) < n_real) out[(size_t)(grow + r) * H + gcol] = outacc[rt][ct][r];
        }
}

// ---------------- launch ----------------

extern "C" void kernel_launch(void* const* d_in, const int* in_sizes, int n_in,
                              void* d_out, int out_size, void* d_ws, size_t ws_size,
                              hipStream_t stream) {
    (void)in_sizes; (void)n_in; (void)out_size; (void)ws_size;
    const float* ent    = (const float*)d_in[0];
    const float* rel    = (const float*)d_in[1];
    const float* w_edge = (const float*)d_in[2];
    const float* w_node = (const float*)d_in[3];
    const float* w_comp = (const float*)d_in[4];
    const float* rel_w  = (const float*)d_in[5];
    const int* src      = (const int*)d_in[6];
    const int* dst      = (const int*)d_in[7];
    const int* rel_id   = (const int*)d_in[8];
    const int* node_id  = (const int*)d_in[9];

    char* wsb = (char*)d_ws;
    size_t o = 0;
    auto alloc = [&](size_t bytes) -> char* {
        char* p = wsb + o;
        o = (o + bytes + 255) & ~(size_t)255;
        return p;
    };
    int* counts  = (int*)alloc((size_t)N_ENT * 4);
    int* offsets = (int*)alloc((size_t)(N_ENT + 1) * 4);
    int* bsum    = (int*)alloc(128 * 4);
    int2* meta   = (int2*)alloc((size_t)E_EDGES * 8);
    int* dbin    = (int*)alloc(DEG_BINS * 4);
    int* doff    = (int*)alloc(DEG_BINS * 4);
    int* dorder  = (int*)alloc((size_t)N_ENT * 4);
    u16* agg_e   = (u16*)alloc((size_t)N_ENT * H * 2);
    u16* agg_n   = (u16*)alloc((size_t)N_ENT * H * 2);
    u16* agg_c   = (u16*)alloc((size_t)N_ENT * H * 2);
    u16* wswz    = (u16*)alloc((size_t)4 * H * H * 2);
    u16* relbf   = (u16*)alloc((size_t)REL_ROWS_PAD * H * 2);
    (void)alloc(65536);  // overrun pad for tail-block A staging reads

    float* out_ent = (float*)d_out;
    float* out_rel = out_ent + (size_t)N_ENT * H;

    hipMemsetAsync(counts, 0, (size_t)N_ENT * 4, stream);
    hipMemsetAsync(dbin, 0, DEG_BINS * 4, stream);
    hist_kernel<<<(E_EDGES + 255) / 256, 256, 0, stream>>>(dst, counts);
    scan1_kernel<<<98, 1024, 0, stream>>>(counts, offsets, bsum);
    scan2_kernel<<<1, 128, 0, stream>>>(bsum, offsets);
    scan3_kernel<<<98, 1024, 0, stream>>>(offsets, bsum);
    deghist_kernel<<<98, 1024, 0, stream>>>(counts, dbin);
    degscan_kernel<<<1, 64, 0, stream>>>(dbin, doff);
    degplace_kernel<<<98, 1024, 0, stream>>>(counts, doff, dorder);
    place_kernel<<<(E_EDGES + 255) / 256, 256, 0, stream>>>(dst, src, rel_id, node_id,
                                                            offsets, counts, meta);
    swz_kernel<<<(4 * H * H + 255) / 256, 256, 0, stream>>>(w_edge, w_node, w_comp, rel_w, wswz);
    relbf_kernel<<<(REL_ROWS_PAD * H + 255) / 256, 256, 0, stream>>>(rel, relbf);
    scatter_kernel<<<N_ENT / 4, 256, 0, stream>>>(ent, rel, meta, node_id, offsets, dorder,
                                                  agg_e, agg_n, agg_c);
    gemm_kernel<<<(N_ENT + 63) / 64, 256, 0, stream>>>(agg_e, agg_n, agg_c,
                                                       wswz, wswz + H * H, wswz + 2 * H * H,
                                                       ent, out_ent, N_ENT, 3, 1);
    gemm_kernel<<<(N_REL2 + 63) / 64, 256, 0, stream>>>(relbf, relbf, relbf,
                                                        wswz + 3 * H * H, wswz + 3 * H * H, wswz + 3 * H * H,
                                                        nullptr, out_rel, N_REL2, 1, 0);
}

// Round 4
// 474.051 us; speedup vs baseline: 2.8500x; 1.0583x over previous
//
#include <hip/hip_runtime.h>
#include <hip/hip_bf16.h>

#define N_ENT  100000
#define N_REL2 1000
#define H      256
#define E_EDGES 320000
#define REL_ROWS_PAD 1024   // 1000 rel rows padded to 64-row multiple
#define DEG_BINS 64

typedef unsigned short u16;
typedef short bf16x8 __attribute__((ext_vector_type(8)));
typedef float floatx4 __attribute__((ext_vector_type(4)));

__device__ __forceinline__ u16 f2bf(float f) {
    unsigned x = __float_as_uint(f);
    unsigned r = (x + 0x7fffu + ((x >> 16) & 1u)) >> 16;  // RNE
    return (u16)r;
}

__device__ __forceinline__ ushort4 pack4(float4 v, float s) {
    return make_ushort4(f2bf(v.x * s), f2bf(v.y * s), f2bf(v.z * s), f2bf(v.w * s));
}

__device__ __forceinline__ float fast_tanh(float x) {
    float e = __expf(2.0f * x);
    return 1.0f - 2.0f * __builtin_amdgcn_rcpf(e + 1.0f);
}

__device__ __forceinline__ void async16(u16* lds, const u16* g) {
    __builtin_amdgcn_global_load_lds(
        (const __attribute__((address_space(1))) void*)g,
        (__attribute__((address_space(3))) void*)lds, 16, 0, 0);
}

__device__ __forceinline__ float dot4(float4 a, float4 b) {
    return (a.x * b.x + a.y * b.y) + (a.z * b.z + a.w * b.w);
}
__device__ __forceinline__ float dot4m(float4 a, float4 b, float4 h) {
    return ((a.x * b.x) * h.x + (a.y * b.y) * h.y) + ((a.z * b.z) * h.z + (a.w * b.w) * h.w);
}
// acc*sc + pr*v
__device__ __forceinline__ float4 sfme(float4 a, float sc, float pr, float4 v) {
    return make_float4(a.x * sc + pr * v.x, a.y * sc + pr * v.y,
                       a.z * sc + pr * v.z, a.w * sc + pr * v.w);
}
// acc*sc + pr*u*v
__device__ __forceinline__ float4 sfme2(float4 a, float sc, float pr, float4 u, float4 v) {
    return make_float4(a.x * sc + (pr * u.x) * v.x, a.y * sc + (pr * u.y) * v.y,
                       a.z * sc + (pr * u.z) * v.z, a.w * sc + (pr * u.w) * v.w);
}

// ---------------- CSR build ----------------

__global__ void hist_kernel(const int* __restrict__ dst, int* __restrict__ counts) {
    int i = blockIdx.x * blockDim.x + threadIdx.x;
    if (i < E_EDGES) atomicAdd(&counts[dst[i]], 1);
}

// scan over counts; also builds the degree histogram (two-level: LDS then global)
__global__ void scan1_kernel(const int* __restrict__ counts, int* __restrict__ offsets,
                             int* __restrict__ bsum, int* __restrict__ dbin) {
    __shared__ int buf[1024];
    __shared__ int lh[DEG_BINS];
    int t = threadIdx.x, i = blockIdx.x * 1024 + t;
    if (t < DEG_BINS) lh[t] = 0;
    int v = (i < N_ENT) ? counts[i] : 0;
    int acc = v;
    buf[t] = acc;
    __syncthreads();
    if (i < N_ENT) {
        int b = v > DEG_BINS - 1 ? DEG_BINS - 1 : v;
        atomicAdd(&lh[b], 1);   // LDS atomic
    }
    for (int off = 1; off < 1024; off <<= 1) {
        int u = (t >= off) ? buf[t - off] : 0;
        __syncthreads();
        acc += u;
        buf[t] = acc;
        __syncthreads();
    }
    if (i < N_ENT) offsets[i] = acc - v;  // exclusive within block
    if (t == 1023) bsum[blockIdx.x] = acc;
    if (t < DEG_BINS && lh[t]) atomicAdd(&dbin[t], lh[t]);  // 64 global atomics/block
}

__global__ void scan2_kernel(int* __restrict__ bsum, int* __restrict__ offsets,
                             const int* __restrict__ dbin, int* __restrict__ doff) {
    __shared__ int s[128];
    int t = threadIdx.x;
    s[t] = (t < 98) ? bsum[t] : 0;
    __syncthreads();
    if (t == 0) {
        int run = 0;
        for (int b = 0; b < 98; ++b) { int x = s[b]; s[b] = run; run += x; }
        offsets[N_ENT] = run;
        int r2 = 0;
        for (int b = 0; b < DEG_BINS; ++b) { int x = dbin[b]; doff[b] = r2; r2 += x; }
    }
    __syncthreads();
    if (t < 98) bsum[t] = s[t];
}

__global__ void scan3_kernel(int* __restrict__ offsets, const int* __restrict__ bsum) {
    int i = blockIdx.x * 1024 + threadIdx.x;
    if (i < N_ENT && blockIdx.x > 0) offsets[i] += bsum[blockIdx.x];
}

// degree-sort placement: LDS rank + one global range-reserve atomic per (block,bin)
__global__ void degplace_kernel(const int* __restrict__ counts, int* __restrict__ doff,
                                int* __restrict__ dorder) {
    __shared__ int lh[DEG_BINS];
    __shared__ int lbase[DEG_BINS];
    int t = threadIdx.x;
    if (t < DEG_BINS) lh[t] = 0;
    __syncthreads();
    int i = blockIdx.x * blockDim.x + t;
    int b = 0, myidx = 0;
    if (i < N_ENT) {
        b = counts[i]; if (b > DEG_BINS - 1) b = DEG_BINS - 1;
        myidx = atomicAdd(&lh[b], 1);  // LDS atomic: intra-block rank
    }
    __syncthreads();
    if (t < DEG_BINS) lbase[t] = lh[t] ? atomicAdd(&doff[t], lh[t]) : 0;  // range reserve
    __syncthreads();
    if (i < N_ENT) dorder[lbase[b] + myidx] = i;
}

// place: resolve the whole per-edge metadata chain HERE (edge-parallel, coalesced
// reads) so scatter's per-edge chain is ONE 8B load: meta[pos] = {node_id[src], rel_id}
__global__ void place_kernel(const int* __restrict__ dst, const int* __restrict__ src,
                             const int* __restrict__ rel_id, const int* __restrict__ node_id,
                             const int* __restrict__ offsets,
                             int* __restrict__ counts, int2* __restrict__ meta) {
    int i = blockIdx.x * blockDim.x + threadIdx.x;
    if (i < E_EDGES) {
        int d = dst[i];
        int old = atomicSub(&counts[d], 1);
        meta[offsets[d] + old - 1] = make_int2(node_id[src[i]], rel_id[i]);
    }
}

// ---------------- weight prep ----------------
// B-fragment order for mfma_f32_16x16x32_bf16 (verified R1 of prior session):
// dst[((ntile*8+kstep)*64+lane)*8+j] = bf16(W[kstep*32+(lane>>4)*8+j][ntile*16+(lane&15)])
__global__ void swz_kernel(const float* __restrict__ w0, const float* __restrict__ w1,
                           const float* __restrict__ w2, const float* __restrict__ w3,
                           u16* __restrict__ dstp) {
    int t = blockIdx.x * blockDim.x + threadIdx.x;
    if (t >= 4 * H * H) return;
    int mat = t >> 16;
    int r = t & 65535;
    int j = r & 7, lane = (r >> 3) & 63, kstep = (r >> 9) & 7, ntile = r >> 12;
    int k = kstep * 32 + (lane >> 4) * 8 + j;
    int n = ntile * 16 + (lane & 15);
    const float* W = (mat == 0) ? w0 : (mat == 1) ? w1 : (mat == 2) ? w2 : w3;
    dstp[t] = f2bf(W[k * H + n]);
}

// rel_emb -> bf16, row-major with intra-row XOR chunk swizzle (same layout as agg):
// u16 index row*256 + kk holds rel[row][kk ^ ((row&7)<<3)]
__global__ void relbf_kernel(const float* __restrict__ rel, u16* __restrict__ out) {
    int t = blockIdx.x * blockDim.x + threadIdx.x;
    if (t >= REL_ROWS_PAD * H) return;
    int row = t >> 8, kk = t & 255;
    int k = kk ^ ((row & 7) << 3);
    float v = (row < N_REL2) ? rel[row * H + k] : 0.f;
    out[t] = f2bf(v);
}

// ---------------- fused per-dst scores + softmax + segment-sum ----------------
// 16-lane-group version: each group of 16 lanes owns ONE destination (16 floats/lane
// = full H row per group); a wave processes 4 dsts concurrently. Degree sort makes
// the 4 groups' trip counts (near-)equal -> negligible intra-wave divergence.
// Reduction is a 4-level in-group butterfly (vs 6-level 64-lane), and all softmax
// scalar work + exp serves 4 edges per wave pass instead of 1.
__global__ __launch_bounds__(256) void scatter_kernel(
    const float* __restrict__ ent, const float* __restrict__ rel,
    const int2* __restrict__ meta, const int* __restrict__ node_id,
    const int* __restrict__ offsets, const int* __restrict__ dorder,
    u16* __restrict__ agg_e, u16* __restrict__ agg_n, u16* __restrict__ agg_c) {
    int lane = threadIdx.x & 63;
    int wv = threadIdx.x >> 6;
    int grp = lane >> 4, sl = lane & 15;
    int w = blockIdx.x * 16 + wv * 4 + grp;   // 6250*16 == 100000 exactly, no guard
    int d = dorder[w];
    int nid = node_id[d];
    int p0 = offsets[d], p1 = offsets[d + 1];
    // interleaved chunk assignment: lane sl holds float4 chunks {sl, 16+sl, 32+sl, 48+sl}
    // -> each load instruction reads 256B contiguous per group (perfect coalescing).
    const float4* hrow = (const float4*)(ent + (size_t)nid * H);
    float4 h0 = hrow[sl], h1 = hrow[16 + sl], h2 = hrow[32 + sl], h3 = hrow[48 + sl];
    float me = -INFINITY, mn = -INFINITY, mc = -INFINITY;
    float le = 0.f, ln = 0.f, lc = 0.f;
    float4 z = make_float4(0.f, 0.f, 0.f, 0.f);
    float4 ae0 = z, ae1 = z, ae2 = z, ae3 = z;
    float4 an0 = z, an1 = z, an2 = z, an3 = z;
    float4 ac0 = z, ac1 = z, ac2 = z, ac3 = z;

    for (int pc = p0; pc < p1; ++pc) {
        int2 md = meta[pc];   // 8B, uniform within group
        const float4* er = (const float4*)(rel + (size_t)md.y * H);
        const float4* sr = (const float4*)(ent + (size_t)md.x * H);
        float4 e0 = er[sl], e1 = er[16 + sl], e2 = er[32 + sl], e3 = er[48 + sl];
        float4 s0 = sr[sl], s1 = sr[16 + sl], s2 = sr[32 + sl], s3 = sr[48 + sl];
        float de = dot4(e0, h0) + dot4(e1, h1) + dot4(e2, h2) + dot4(e3, h3);
        float dn = dot4(s0, h0) + dot4(s1, h1) + dot4(s2, h2) + dot4(s3, h3);
        float dc = dot4m(e0, s0, h0) + dot4m(e1, s1, h1) + dot4m(e2, s2, h2) + dot4m(e3, s3, h3);
#pragma unroll
        for (int o = 8; o; o >>= 1) {   // in-group butterfly (xor<16 stays in group)
            de += __shfl_xor(de, o);
            dn += __shfl_xor(dn, o);
            dc += __shfl_xor(dc, o);
        }
        { float nm = fmaxf(me, de); float sc = __expf(me - nm); float pr = __expf(de - nm);
          le = le * sc + pr;
          ae0 = sfme(ae0, sc, pr, e0); ae1 = sfme(ae1, sc, pr, e1);
          ae2 = sfme(ae2, sc, pr, e2); ae3 = sfme(ae3, sc, pr, e3); me = nm; }
        { float nm = fmaxf(mn, dn); float sc = __expf(mn - nm); float pr = __expf(dn - nm);
          ln = ln * sc + pr;
          an0 = sfme(an0, sc, pr, s0); an1 = sfme(an1, sc, pr, s1);
          an2 = sfme(an2, sc, pr, s2); an3 = sfme(an3, sc, pr, s3); mn = nm; }
        { float nm = fmaxf(mc, dc); float sc = __expf(mc - nm); float pr = __expf(dc - nm);
          lc = lc * sc + pr;
          ac0 = sfme2(ac0, sc, pr, e0, s0); ac1 = sfme2(ac1, sc, pr, e1, s1);
          ac2 = sfme2(ac2, sc, pr, e2, s2); ac3 = sfme2(ac3, sc, pr, e3, s3); mc = nm; }
    }
    float ie  = (le > 0.f) ? 1.0f / le : 0.f;
    float in_ = (ln > 0.f) ? 1.0f / ln : 0.f;
    float ic  = (lc > 0.f) ? 1.0f / lc : 0.f;
    // store: feature f of row d at byte 2f ^ ((d&7)<<4) — same convention as before,
    // so the GEMM stage/read path is unchanged. Lane sl's chunk q = logical bytes
    // q*128 + sl*8 (8B each); XOR flips bits 4-6 only, 8B alignment preserved.
    size_t rowb = (size_t)d * 512;
    int swz = (d & 7) << 4;
    int b0 = sl * 8;
    *(ushort4*)((char*)agg_e + rowb + ((b0      ) ^ swz)) = pack4(ae0, ie);
    *(ushort4*)((char*)agg_e + rowb + ((b0 + 128) ^ swz)) = pack4(ae1, ie);
    *(ushort4*)((char*)agg_e + rowb + ((b0 + 256) ^ swz)) = pack4(ae2, ie);
    *(ushort4*)((char*)agg_e + rowb + ((b0 + 384) ^ swz)) = pack4(ae3, ie);
    *(ushort4*)((char*)agg_n + rowb + ((b0      ) ^ swz)) = pack4(an0, in_);
    *(ushort4*)((char*)agg_n + rowb + ((b0 + 128) ^ swz)) = pack4(an1, in_);
    *(ushort4*)((char*)agg_n + rowb + ((b0 + 256) ^ swz)) = pack4(an2, in_);
    *(ushort4*)((char*)agg_n + rowb + ((b0 + 384) ^ swz)) = pack4(an3, in_);
    *(ushort4*)((char*)agg_c + rowb + ((b0      ) ^ swz)) = pack4(ac0, ic);
    *(ushort4*)((char*)agg_c + rowb + ((b0 + 128) ^ swz)) = pack4(ac1, ic);
    *(ushort4*)((char*)agg_c + rowb + ((b0 + 256) ^ swz)) = pack4(ac2, ic);
    *(ushort4*)((char*)agg_c + rowb + ((b0 + 384) ^ swz)) = pack4(ac3, ic);
}

// ---------------- fused multi-layer GEMM epilogue ----------------
// out[r,:] = base[r,:] + sum_l tanh(A_l[r,:] @ W_l)   (raw if !do_tanh)
// 64 rows x 256 cols per block, 4 waves; A rows staged linearly to LDS (rows are
// pre-swizzled in global, rule #21), fragments read with the inverse XOR.
__global__ __launch_bounds__(256, 2) void gemm_kernel(
    const u16* __restrict__ A0, const u16* __restrict__ A1, const u16* __restrict__ A2,
    const u16* __restrict__ W0, const u16* __restrict__ W1, const u16* __restrict__ W2,
    const float* __restrict__ base, float* __restrict__ out,
    int n_real, int n_layers, int do_tanh) {
    __shared__ u16 lA[2][16384];  // 2 x 32KB: 64 rows x 512B row-major (swizzled)
    int tid = threadIdx.x;
    int lane = tid & 63;
    int wv = tid >> 6;
    int m = lane & 15;
    int quad = lane >> 4;
    int r0 = blockIdx.x * 64;
    const u16* As[3] = { A0, A1, A2 };
    const u16* Ws[3] = { W0, W1, W2 };

    float outacc[4][4][4];
#pragma unroll
    for (int rt = 0; rt < 4; ++rt)
#pragma unroll
        for (int ct = 0; ct < 4; ++ct) {
            int grow = r0 + rt * 16 + quad * 4;
            int gcol = wv * 64 + ct * 16 + m;
#pragma unroll
            for (int r = 0; r < 4; ++r) {
                float v = 0.f;
                if (base != nullptr && (grow + r) < n_real) v = base[(size_t)(grow + r) * H + gcol];
                outacc[rt][ct][r] = v;
            }
        }

    // stage layer 0 into buf 0 (linear 32KB copy, async to LDS)
    {
        const u16* gsrc = As[0] + (size_t)blockIdx.x * 64 * H;
#pragma unroll
        for (int rnd = 0; rnd < 8; ++rnd) {
            int off8 = (rnd * 256 + tid) * 8;
            async16(&lA[0][off8], gsrc + off8);
        }
    }

    int mrow = m * 512;          // row byte base within a 16-row fragment
    int swz = (m & 7) << 4;      // inverse of the store-side XOR

    for (int l = 0; l < n_layers; ++l) {
        __syncthreads();  // buf[l&1] staged; prev layer's ds_reads complete
        if (l + 1 < n_layers) {
            const u16* gsrc = As[l + 1] + (size_t)blockIdx.x * 64 * H;
            u16* dstb = lA[(l + 1) & 1];
#pragma unroll
            for (int rnd = 0; rnd < 8; ++rnd) {
                int off8 = (rnd * 256 + tid) * 8;
                async16(&dstb[off8], gsrc + off8);
            }
        }
        const char* lbc = (const char*)lA[l & 1];
        const u16* Wl = Ws[l];

        floatx4 lacc[4][4];
#pragma unroll
        for (int rt = 0; rt < 4; ++rt)
#pragma unroll
            for (int ct = 0; ct < 4; ++ct)
#pragma unroll
                for (int r = 0; r < 4; ++r) lacc[rt][ct][r] = 0.f;

#pragma unroll
        for (int ks = 0; ks < 8; ++ks) {
            bf16x8 af[4], bfr[4];
#pragma unroll
            for (int rt = 0; rt < 4; ++rt)
                af[rt] = *(const bf16x8*)(lbc + rt * 8192 + mrow + ((ks * 64 + quad * 16) ^ swz));
#pragma unroll
            for (int ct = 0; ct < 4; ++ct)
                bfr[ct] = *(const bf16x8*)(Wl + (((size_t)(wv * 4 + ct) * 8 + ks) * 64 + lane) * 8);
#pragma unroll
            for (int rt = 0; rt < 4; ++rt)
#pragma unroll
                for (int ct = 0; ct < 4; ++ct)
                    lacc[rt][ct] = __builtin_amdgcn_mfma_f32_16x16x32_bf16(
                        af[rt], bfr[ct], lacc[rt][ct], 0, 0, 0);
        }

#pragma unroll
        for (int rt = 0; rt < 4; ++rt)
#pragma unroll
            for (int ct = 0; ct < 4; ++ct)
#pragma unroll
                for (int r = 0; r < 4; ++r) {
                    float v = lacc[rt][ct][r];
                    outacc[rt][ct][r] += do_tanh ? fast_tanh(v) : v;
                }
    }

#pragma unroll
    for (int rt = 0; rt < 4; ++rt)
#pragma unroll
        for (int ct = 0; ct < 4; ++ct) {
            int grow = r0 + rt * 16 + quad * 4;
            int gcol = wv * 64 + ct * 16 + m;
#pragma unroll
            for (int r = 0; r < 4; ++r)
                if ((grow + r) < n_real) out[(size_t)(grow + r) * H + gcol] = outacc[rt][ct][r];
        }
}

// ---------------- launch ----------------

extern "C" void kernel_launch(void* const* d_in, const int* in_sizes, int n_in,
                              void* d_out, int out_size, void* d_ws, size_t ws_size,
                              hipStream_t stream) {
    (void)in_sizes; (void)n_in; (void)out_size; (void)ws_size;
    const float* ent    = (const float*)d_in[0];
    const float* rel    = (const float*)d_in[1];
    const float* w_edge = (const float*)d_in[2];
    const float* w_node = (const float*)d_in[3];
    const float* w_comp = (const float*)d_in[4];
    const float* rel_w  = (const float*)d_in[5];
    const int* src      = (const int*)d_in[6];
    const int* dst      = (const int*)d_in[7];
    const int* rel_id   = (const int*)d_in[8];
    const int* node_id  = (const int*)d_in[9];

    char* wsb = (char*)d_ws;
    size_t o = 0;
    auto alloc = [&](size_t bytes) -> char* {
        char* p = wsb + o;
        o = (o + bytes + 255) & ~(size_t)255;
        return p;
    };
    int* counts  = (int*)alloc((size_t)N_ENT * 4);
    int* offsets = (int*)alloc((size_t)(N_ENT + 1) * 4);
    int* bsum    = (int*)alloc(128 * 4);
    int2* meta   = (int2*)alloc((size_t)E_EDGES * 8);
    int* dbin    = (int*)alloc(DEG_BINS * 4);
    int* doff    = (int*)alloc(DEG_BINS * 4);
    int* dorder  = (int*)alloc((size_t)N_ENT * 4);
    u16* agg_e   = (u16*)alloc((size_t)N_ENT * H * 2);
    u16* agg_n   = (u16*)alloc((size_t)N_ENT * H * 2);
    u16* agg_c   = (u16*)alloc((size_t)N_ENT * H * 2);
    u16* wswz    = (u16*)alloc((size_t)4 * H * H * 2);
    u16* relbf   = (u16*)alloc((size_t)REL_ROWS_PAD * H * 2);
    (void)alloc(65536);  // overrun pad for tail-block A staging reads

    float* out_ent = (float*)d_out;
    float* out_rel = out_ent + (size_t)N_ENT * H;

    hipMemsetAsync(counts, 0, (size_t)N_ENT * 4, stream);
    hipMemsetAsync(dbin, 0, DEG_BINS * 4, stream);
    hist_kernel<<<(E_EDGES + 255) / 256, 256, 0, stream>>>(dst, counts);
    scan1_kernel<<<98, 1024, 0, stream>>>(counts, offsets, bsum, dbin);
    scan2_kernel<<<1, 128, 0, stream>>>(bsum, offsets, dbin, doff);
    scan3_kernel<<<98, 1024, 0, stream>>>(offsets, bsum);
    degplace_kernel<<<98, 1024, 0, stream>>>(counts, doff, dorder);
    place_kernel<<<(E_EDGES + 255) / 256, 256, 0, stream>>>(dst, src, rel_id, node_id,
                                                            offsets, counts, meta);
    swz_kernel<<<(4 * H * H + 255) / 256, 256, 0, stream>>>(w_edge, w_node, w_comp, rel_w, wswz);
    relbf_kernel<<<(REL_ROWS_PAD * H + 255) / 256, 256, 0, stream>>>(rel, relbf);
    scatter_kernel<<<N_ENT / 16, 256, 0, stream>>>(ent, rel, meta, node_id, offsets, dorder,
                                                   agg_e, agg_n, agg_c);
    gemm_kernel<<<(N_ENT + 63) / 64, 256, 0, stream>>>(agg_e, agg_n, agg_c,
                                                       wswz, wswz + H * H, wswz + 2 * H * H,
                                                       ent, out_ent, N_ENT, 3, 1);
    gemm_kernel<<<(N_REL2 + 63) / 64, 256, 0, stream>>>(relbf, relbf, relbf,
                                                        wswz + 3 * H * H, wswz + 3 * H * H, wswz + 3 * H * H,
                                                        nullptr, out_rel, N_REL2, 1, 0);
}